// Round 11
// baseline (437.693 us; speedup 1.0000x reference)
//
#include <hip/hip_runtime.h>
#include <math.h>

// Problem constants (from reference)
#define NDIM 64
#define NK   128
#define ALPHA_DP 1.0
#define TAU0 0.0
#define C0v  1.0
#define N0v  ((double)(NDIM + 2))
#define B0v  1.0

#define ITERS 4          // 256-point iterations per block (grid = N/1024 = 256 = 1 block/CU)
#define NSLOT 64         // ll partial-sum slots

typedef __attribute__((ext_vector_type(8))) short bf16x8;
typedef __attribute__((ext_vector_type(4))) float f32x4;

// ---------------- device math helpers ----------------
__device__ double digamma_d(double x) {
    double r = 0.0;
    while (x < 6.0) { r -= 1.0 / x; x += 1.0; }
    double inv = 1.0 / x, inv2 = inv * inv;
    double s = log(x) - 0.5 * inv
        - inv2 * (1.0/12.0 - inv2 * (1.0/120.0 - inv2 * (1.0/252.0
            - inv2 * (1.0/240.0 - inv2 * (1.0/132.0)))));
    return s + r;
}

__device__ inline unsigned pack_bf16_hi(float a, float b) {
    // dword = {bf16(a) lo16, bf16(b) hi16}; truncation split
    return (__float_as_uint(a) >> 16) | (__float_as_uint(b) & 0xffff0000u);
}

// DPP cross-lane mov (VALU pipe). CTRL compile-time (builtin requirement).
// 0xB1=quad xor1, 0x4E=quad xor2, 0x124=row_ror:4, 0x128=row_ror:8.
// xor1+xor2+ror4+ror8 = full 16-lane-row reduce (all lanes get the total).
template <int CTRL>
__device__ inline float dpp_mov(float v) {
    return __uint_as_float((unsigned)__builtin_amdgcn_update_dpp(
        0, (int)__float_as_uint(v), CTRL, 0xF, 0xF, true));
}

// fragment-major ushort index for W tables, 16x16x32 MFMA B-operand layout:
// feature f (0..127: x dims then y dims), cluster k.
// B-frag: lane(hi=l>>4, n=l&15) holds B[k = s*32 + hi*8 + j][col = t*16 + n].
// layout: [s=f>>5][t=k>>4][hi=(f>>3)&3][n=k&15][j=f&7]
__device__ inline int widx(int f, int k) {
    int s = f >> 5, hi = (f >> 3) & 3, j = f & 7, t = k >> 4, n = k & 15;
    return (((s * 8 + t) * 4 + hi) * 16 + n) * 8 + j;
}

// ---------------- kernel 1: cluster prep (1 block, 1024 threads) ----------------
// 8 lanes per cluster, 8 dims per lane; transcendentals lane-specialized
// (each lane: exactly 1 digamma + 1 lgamma); 8-lane shuffle reductions.
// ws: scal[2] dbl | slots[64] dbl | constk[128] f32 | Wh (32KB) | Wl (32KB)
__global__ __launch_bounds__(1024) void prep_kernel(
    const float* __restrict__ nat_u,
    const float* __restrict__ nat_v,
    const float* __restrict__ nat_tau,
    const float* __restrict__ nat_c,
    const float* __restrict__ nat_n,
    const float* __restrict__ nat_B,
    double* __restrict__ scal,
    double* __restrict__ slots,
    float* __restrict__ constk,
    unsigned short* __restrict__ Wh,
    unsigned short* __restrict__ Wl) {
    const int t = threadIdx.x;
    const int k = t >> 3;            // cluster 0..127
    const int j = t & 7;             // sub-lane within cluster
    const int D = NDIM;

    double u = (double)nat_u[k] + 1.0;
    double v = (double)nat_v[k] + 1.0;
    double c = (double)nat_c[k];
    double n = (double)nat_n[k] - (double)D - 2.0;
    double a1 = 0.5 * n;
    const double a0g = 0.5 * N0v;    // 33.0
    const double b0g = 0.5 * B0v;    // 0.5
    const double log_b0g = log(b0g);

    double s_logB = 0.0, s_t2nb = 0.0, s_nb = 0.0, s_klg = 0.0, s_kln = 0.0;

#pragma unroll
    for (int i = 0; i < 8; ++i) {
        int d = j * 8 + i;
        double tau = (double)nat_tau[k * D + d] / c;
        double B   = (double)nat_B[k * D + d] - c * tau * tau;
        double nb  = n / B;
        float wx = (float)(tau * nb);          // coefficient on x_d   (feature d)
        float wy = (float)(-0.5 * nb);         // coefficient on y_d=x_d^2-1 (feature 64+d)
        unsigned bx = __float_as_uint(wx), by = __float_as_uint(wy);
        float hx = __uint_as_float(bx & 0xffff0000u);
        float hy = __uint_as_float(by & 0xffff0000u);
        Wh[widx(d, k)]      = (unsigned short)(bx >> 16);
        Wh[widx(64 + d, k)] = (unsigned short)(by >> 16);
        Wl[widx(d, k)]      = (unsigned short)(__float_as_uint(wx - hx) >> 16);
        Wl[widx(64 + d, k)] = (unsigned short)(__float_as_uint(wy - hy) >> 16);

        double b1 = 0.5 * B;
        double lb1 = log(b1);
        s_logB += lb1;
        s_t2nb += tau * tau * nb;
        s_nb   += nb;
        s_klg  += a0g * (lb1 - log_b0g) + a1 * (b0g - b1) / b1;
        s_kln  += C0v * nb * (tau - TAU0) * (tau - TAU0);
    }

    // reduce across the 8 sub-lanes of this cluster (consecutive lanes in wave)
#pragma unroll
    for (int m = 1; m < 8; m <<= 1) {
        s_logB += __shfl_xor(s_logB, m, 64);
        s_t2nb += __shfl_xor(s_t2nb, m, 64);
        s_nb   += __shfl_xor(s_nb,   m, 64);
        s_klg  += __shfl_xor(s_klg,  m, 64);
        s_kln  += __shfl_xor(s_kln,  m, 64);
    }

    // lane-specialized transcendentals: 1 digamma + 1 lgamma per lane
    double arg1 = (j == 0) ? u : (j == 1) ? v : (j == 2) ? (u + v) : a1;
    double dg = digamma_d(arg1);
    double arg2 = (j == 4) ? u : (j == 5) ? v : (j == 6) ? (u + v)
                : (j == 7) ? a1 : a0g;
    double lg = lgamma(arg2);

    const int base = (t & 63) & ~7;  // base lane of this cluster's 8-lane group
    double dg_u   = __shfl(dg, base + 0, 64);
    double dg_v   = __shfl(dg, base + 1, 64);
    double dg_uv  = __shfl(dg, base + 2, 64);
    double dg_a1  = __shfl(dg, base + 3, 64);
    double lg_a0g = __shfl(lg, base + 0, 64);
    double lg_u   = __shfl(lg, base + 4, 64);
    double lg_v   = __shfl(lg, base + 5, 64);
    double lg_uv  = __shfl(lg, base + 6, 64);
    double lg_a1  = __shfl(lg, base + 7, 64);

    __shared__ double sh_stick[NK], sh_cp[NK], sh_kl[NK];
    if (j == 0) {
        const double LOG2PI = 1.8378770664093454836;
        double e_log_det = (double)D * dg_a1 - s_logB;
        // ck without the cross-cluster stick prefix (added below)
        double cp = dg_u - dg_uv + 0.5 * (e_log_det - (double)D * LOG2PI
                    - s_t2nb - (double)D / c - s_nb);
        // KL(Beta(u,v)||Beta(1,1)): constant term lgamma(2)-2*lgamma(1) = 0
        double kl_beta = lg_uv - lg_u - lg_v
            + (u - 1.0) * dg_u + (v - 1.0) * dg_v + (2.0 - u - v) * dg_uv;
        double kl_gamma = (double)D * ((a1 - a0g) * dg_a1 - lg_a1 + lg_a0g) + s_klg;
        double kl_norm = 0.5 * ((double)D * (log(c / C0v) + C0v / c - 1.0) + s_kln);
        sh_stick[k] = dg_v - dg_uv;
        sh_cp[k]    = cp;
        sh_kl[k]    = kl_beta + kl_gamma + kl_norm;
    }
    if (t < NSLOT) slots[t] = 0.0;   // zero ll partials (ws is poisoned)
    __syncthreads();

    if (t < NK) {
        double pre = 0.0;
        for (int q = 0; q < t; ++q) pre += sh_stick[q];   // exclusive prefix
        constk[t] = (float)(sh_cp[t] + pre);
    }
    if (t == 0) {
        double tot = 0.0;
        for (int q = 0; q < NK; ++q) tot += sh_kl[q];
        scal[1] = tot;
        scal[0] = 0.0;
    }
}

// ---------------- kernel 2: barrier-free MFMA maha + in-wave softmax ----------------
// RESTRUCTURE for occupancy (the session-long limiter): 16x16x32 MFMA,
// 16 points/wave (was 32). Accumulator 32 AGPR (was 64), live x-state 16
// floats (was 32) -> max-live ~115 regs fits __launch_bounds__(1024,4)'s
// 128-reg cap WITHOUT spill -> 4 waves/SIMD = 16 waves/CU (2x rounds 0-10).
// One 1024-thread block/CU (grid 256): W tables fully in LDS (64KB, the
// proven fastest W path) + 16x2KB store staging = 96KB <= 160KB.
// Softmax reduce domain = 16 consecutive lanes -> ALL-DPP (zero DS shuffles).
// Full-row r stores kept (r10's RMW fix: -61us): stage via swizzled LDS,
// each 16-lane group stores one full 512B row per instruction pair.
__global__ __launch_bounds__(1024, 4) void maha_kernel(
    const float* __restrict__ x,
    const float* __restrict__ constk,
    const uint4* __restrict__ Wg,      // Wh then Wl, 64 KB fragment-major
    float* __restrict__ r,
    double* __restrict__ slots) {
    __shared__ __align__(16) uint4 W[4096];          // 64 KB: Wh [0,32K), Wl [32K,64K)
    __shared__ __align__(16) float SB[16][512];      // 32 KB store-transpose staging
    const int tid = threadIdx.x;
#pragma unroll
    for (int i = 0; i < 4; ++i) W[i * 1024 + tid] = Wg[i * 1024 + tid];
    __syncthreads();                                  // only barrier in the kernel
    const unsigned short* Wh = (const unsigned short*)W;   // Wl at ushort ofs 16384

    const int lane = tid & 63;
    const int w    = tid >> 6;        // wave 0..15
    const int hi   = lane >> 4;       // k-group / row-group 0..3
    const int n    = lane & 15;       // point row within wave-tile / col within cluster-tile
    float* sb = SB[w];

    float ck[8];
#pragma unroll
    for (int t = 0; t < 8; ++t) ck[t] = constk[t * 16 + n];

    double dsum = 0.0;

#pragma unroll 1
    for (int it = 0; it < ITERS; ++it) {
        const long n0 = (long)blockIdx.x * (256 * ITERS) + it * 256 + w * 16;

        // A-frag x data: lane(hi,n) needs dims hi*8..+8 (sliceA) and
        // 32+hi*8..+8 (sliceB) of point row n0+n. 16 floats total.
        const float* xr = x + (n0 + n) * NDIM + hi * 8;
        f32x4 xa0 = *(const f32x4*)(xr);
        f32x4 xa1 = *(const f32x4*)(xr + 4);
        f32x4 xb0 = *(const f32x4*)(xr + 32);
        f32x4 xb1 = *(const f32x4*)(xr + 36);

        f32x4 acc[8];                 // 8 cluster-tiles x 4 rows
#pragma unroll
        for (int t = 0; t < 8; ++t) {
            acc[t][0] = 0.f; acc[t][1] = 0.f; acc[t][2] = 0.f; acc[t][3] = 0.f;
        }

        // ---- K loop: 4 ksteps (s=0: x lo-dims, 1: x hi-dims, 2: y lo, 3: y hi) ----
#pragma unroll
        for (int s = 0; s < 4; ++s) {
            float fe[8], lo[8];
#pragma unroll
            for (int e = 0; e < 8; ++e) {
                float xv = (s & 1) ? ((e < 4) ? xb0[e] : xb1[e - 4])
                                   : ((e < 4) ? xa0[e] : xa1[e - 4]);
                fe[e] = (s < 2) ? xv : fmaf(xv, xv, -1.0f);   // x or y=x^2-1
            }
#pragma unroll
            for (int e = 0; e < 8; ++e) {
                float h = __uint_as_float(__float_as_uint(fe[e]) & 0xffff0000u);
                lo[e] = fe[e] - h;
            }
            union { bf16x8 v; unsigned d[4]; } ah, al;
#pragma unroll
            for (int q = 0; q < 4; ++q) {
                ah.d[q] = pack_bf16_hi(fe[2 * q], fe[2 * q + 1]);
                al.d[q] = pack_bf16_hi(lo[2 * q], lo[2 * q + 1]);
            }
            __builtin_amdgcn_s_setprio(1);
#pragma unroll
            for (int t = 0; t < 8; ++t) {
                const int bo = ((s * 8 + t) * 4 + hi) * 128 + n * 8;
                bf16x8 bh = *(const bf16x8*)(Wh + bo);
                bf16x8 bl = *(const bf16x8*)(Wh + 16384 + bo);
                acc[t] = __builtin_amdgcn_mfma_f32_16x16x32_bf16(ah.v, bh, acc[t], 0, 0, 0);
                acc[t] = __builtin_amdgcn_mfma_f32_16x16x32_bf16(al.v, bh, acc[t], 0, 0, 0);
                acc[t] = __builtin_amdgcn_mfma_f32_16x16x32_bf16(ah.v, bl, acc[t], 0, 0, 0);
            }
            __builtin_amdgcn_s_setprio(0);
        }

        // ---- softmax + full-row store, per reg (4 rows at a time, one per group) ----
        // C/D: col = n (cluster t*16+n), row = hi*4 + reg (m89-verified layout).
        // Reduce over 128 clusters = 8 local values + 16-lane all-DPP butterfly.
#pragma unroll
        for (int reg = 0; reg < 4; ++reg) {
            float l[8];
#pragma unroll
            for (int t = 0; t < 8; ++t) l[t] = acc[t][reg] + ck[t];
            float M = fmaxf(fmaxf(fmaxf(l[0], l[1]), fmaxf(l[2], l[3])),
                            fmaxf(fmaxf(l[4], l[5]), fmaxf(l[6], l[7])));
            M = fmaxf(M, dpp_mov<0xB1>(M));    // xor1
            M = fmaxf(M, dpp_mov<0x4E>(M));    // xor2
            M = fmaxf(M, dpp_mov<0x124>(M));   // row_ror:4
            M = fmaxf(M, dpp_mov<0x128>(M));   // row_ror:8
            float e[8];
#pragma unroll
            for (int t = 0; t < 8; ++t) e[t] = __expf(l[t] - M);
            float S = ((e[0] + e[1]) + (e[2] + e[3])) + ((e[4] + e[5]) + (e[6] + e[7]));
            S += dpp_mov<0xB1>(S);
            S += dpp_mov<0x4E>(S);
            S += dpp_mov<0x124>(S);
            S += dpp_mov<0x128>(S);
            const float inv = __builtin_amdgcn_rcpf(S);

            // stage row hi (swizzled col (c+4hi)&127 breaks write bank aliasing)
#pragma unroll
            for (int t = 0; t < 8; ++t)
                sb[hi * 128 + ((16 * t + n + 4 * hi) & 127)] = e[t] * inv;
            // read back 8 consecutive logical cols (two aligned b128, wrap-safe)
            const int c0 = (8 * n + 4 * hi) & 127;
            const int c1 = (c0 + 4) & 127;
            f32x4 v0 = *(const f32x4*)(sb + hi * 128 + c0);
            f32x4 v1 = *(const f32x4*)(sb + hi * 128 + c1);
            float* rp = r + (n0 + hi * 4 + reg) * (long)NK + n * 8;
            *(f32x4*)(rp)     = v0;   // 16-lane group covers one full 512B row
            *(f32x4*)(rp + 4) = v1;
            dsum += (double)(M + __logf(S));   // uniform within 16-lane group
        }
    }

    // ---- ll: each group covers distinct rows; combine 4 groups, 1 atomic/wave ----
    double dtot = __shfl(dsum, 0, 64) + __shfl(dsum, 16, 64)
                + __shfl(dsum, 32, 64) + __shfl(dsum, 48, 64);
    if (lane == 0) atomicAdd(&slots[(blockIdx.x * 16 + w) & (NSLOT - 1)], dtot);
}

// ---------------- kernel 3: finalize scalar ----------------
__global__ void finalize_kernel(const double* __restrict__ scal,
                                const double* __restrict__ slots,
                                float* __restrict__ out) {
    double ll = 0.0;
    for (int i = 0; i < NSLOT; ++i) ll += slots[i];
    out[0] = (float)(scal[1] - ll);   // -elbo = kl_total - ll
}

extern "C" void kernel_launch(void* const* d_in, const int* in_sizes, int n_in,
                              void* d_out, int out_size, void* d_ws, size_t ws_size,
                              hipStream_t stream) {
    const float* x       = (const float*)d_in[0];
    const float* nat_u   = (const float*)d_in[1];
    const float* nat_v   = (const float*)d_in[2];
    const float* nat_tau = (const float*)d_in[3];
    const float* nat_c   = (const float*)d_in[4];
    const float* nat_n   = (const float*)d_in[5];
    const float* nat_B   = (const float*)d_in[6];

    const int N = in_sizes[0] / NDIM;
    float* out = (float*)d_out;

    // ws layout: scal 16B | slots 512B | constk 512B | Wh 32KB | Wl 32KB (16B-aligned)
    double* scal       = (double*)d_ws;
    double* slots      = (double*)((char*)d_ws + 16);
    float* constk      = (float*)((char*)d_ws + 16 + 512);
    unsigned short* Wh = (unsigned short*)((char*)d_ws + 1040);
    unsigned short* Wl = (unsigned short*)((char*)d_ws + 1040 + 32768);
    const uint4* Wg    = (const uint4*)((char*)d_ws + 1040);

    prep_kernel<<<1, 1024, 0, stream>>>(nat_u, nat_v, nat_tau, nat_c, nat_n, nat_B,
                                        scal, slots, constk, Wh, Wl);
    maha_kernel<<<N / (256 * ITERS), 1024, 0, stream>>>(x, constk, Wg, out, slots);
    finalize_kernel<<<1, 1, 0, stream>>>(scal, slots, out + (size_t)N * NK);
}

// Round 12
// 288.832 us; speedup vs baseline: 1.5154x; 1.5154x over previous
//
#include <hip/hip_runtime.h>
#include <math.h>

// Problem constants (from reference)
#define NDIM 64
#define NK   128
#define ALPHA_DP 1.0
#define TAU0 0.0
#define C0v  1.0
#define N0v  ((double)(NDIM + 2))
#define B0v  1.0

#define ITERS 4          // 128-point iterations per block (grid = N/512 = 512)
#define NSLOT 64         // ll partial-sum slots

typedef __attribute__((ext_vector_type(8))) short bf16x8;
typedef __attribute__((ext_vector_type(4))) float f32x4;

// ---------------- device math helpers ----------------
__device__ double digamma_d(double x) {
    double r = 0.0;
    while (x < 6.0) { r -= 1.0 / x; x += 1.0; }
    double inv = 1.0 / x, inv2 = inv * inv;
    double s = log(x) - 0.5 * inv
        - inv2 * (1.0/12.0 - inv2 * (1.0/120.0 - inv2 * (1.0/252.0
            - inv2 * (1.0/240.0 - inv2 * (1.0/132.0)))));
    return s + r;
}

__device__ inline unsigned pack_bf16_hi(float a, float b) {
    // dword = {bf16(a) lo16, bf16(b) hi16}; truncation split
    return (__float_as_uint(a) >> 16) | (__float_as_uint(b) & 0xffff0000u);
}

// DPP cross-lane mov (VALU pipe). CTRL compile-time (builtin requirement).
// 0xB1=quad xor1, 0x4E=quad xor2, 0x124=row_ror:4, 0x128=row_ror:8.
// xor1+xor2+ror4+ror8 = full 16-lane-row reduce (all lanes get the total).
template <int CTRL>
__device__ inline float dpp_mov(float v) {
    return __uint_as_float((unsigned)__builtin_amdgcn_update_dpp(
        0, (int)__float_as_uint(v), CTRL, 0xF, 0xF, true));
}

// fragment-major ushort index for W tables, 16x16x32 MFMA B-operand layout:
// feature f (0..127: x dims then y dims), cluster k.
// B-frag: lane(hi=l>>4, n=l&15) holds B[k = hi*8 + j][col = n] of K-step s.
// layout: [s=f>>5][t=k>>4][hi=(f>>3)&3][n=k&15][j=f&7]
__device__ inline int widx(int f, int k) {
    int s = f >> 5, hi = (f >> 3) & 3, j = f & 7, t = k >> 4, n = k & 15;
    return (((s * 8 + t) * 4 + hi) * 16 + n) * 8 + j;
}

// ---------------- kernel 1: cluster prep (1 block, 1024 threads) ----------------
__global__ __launch_bounds__(1024) void prep_kernel(
    const float* __restrict__ nat_u,
    const float* __restrict__ nat_v,
    const float* __restrict__ nat_tau,
    const float* __restrict__ nat_c,
    const float* __restrict__ nat_n,
    const float* __restrict__ nat_B,
    double* __restrict__ scal,
    double* __restrict__ slots,
    float* __restrict__ constk,
    unsigned short* __restrict__ Wh,
    unsigned short* __restrict__ Wl) {
    const int t = threadIdx.x;
    const int k = t >> 3;            // cluster 0..127
    const int j = t & 7;             // sub-lane within cluster
    const int D = NDIM;

    double u = (double)nat_u[k] + 1.0;
    double v = (double)nat_v[k] + 1.0;
    double c = (double)nat_c[k];
    double n = (double)nat_n[k] - (double)D - 2.0;
    double a1 = 0.5 * n;
    const double a0g = 0.5 * N0v;    // 33.0
    const double b0g = 0.5 * B0v;    // 0.5
    const double log_b0g = log(b0g);

    double s_logB = 0.0, s_t2nb = 0.0, s_nb = 0.0, s_klg = 0.0, s_kln = 0.0;

#pragma unroll
    for (int i = 0; i < 8; ++i) {
        int d = j * 8 + i;
        double tau = (double)nat_tau[k * D + d] / c;
        double B   = (double)nat_B[k * D + d] - c * tau * tau;
        double nb  = n / B;
        float wx = (float)(tau * nb);          // coefficient on x_d   (feature d)
        float wy = (float)(-0.5 * nb);         // coefficient on y_d=x_d^2-1 (feature 64+d)
        unsigned bx = __float_as_uint(wx), by = __float_as_uint(wy);
        float hx = __uint_as_float(bx & 0xffff0000u);
        float hy = __uint_as_float(by & 0xffff0000u);
        Wh[widx(d, k)]      = (unsigned short)(bx >> 16);
        Wh[widx(64 + d, k)] = (unsigned short)(by >> 16);
        Wl[widx(d, k)]      = (unsigned short)(__float_as_uint(wx - hx) >> 16);
        Wl[widx(64 + d, k)] = (unsigned short)(__float_as_uint(wy - hy) >> 16);

        double b1 = 0.5 * B;
        double lb1 = log(b1);
        s_logB += lb1;
        s_t2nb += tau * tau * nb;
        s_nb   += nb;
        s_klg  += a0g * (lb1 - log_b0g) + a1 * (b0g - b1) / b1;
        s_kln  += C0v * nb * (tau - TAU0) * (tau - TAU0);
    }

    // reduce across the 8 sub-lanes of this cluster (consecutive lanes in wave)
#pragma unroll
    for (int m = 1; m < 8; m <<= 1) {
        s_logB += __shfl_xor(s_logB, m, 64);
        s_t2nb += __shfl_xor(s_t2nb, m, 64);
        s_nb   += __shfl_xor(s_nb,   m, 64);
        s_klg  += __shfl_xor(s_klg,  m, 64);
        s_kln  += __shfl_xor(s_kln,  m, 64);
    }

    // lane-specialized transcendentals: 1 digamma + 1 lgamma per lane
    double arg1 = (j == 0) ? u : (j == 1) ? v : (j == 2) ? (u + v) : a1;
    double dg = digamma_d(arg1);
    double arg2 = (j == 4) ? u : (j == 5) ? v : (j == 6) ? (u + v)
                : (j == 7) ? a1 : a0g;
    double lg = lgamma(arg2);

    const int base = (t & 63) & ~7;  // base lane of this cluster's 8-lane group
    double dg_u   = __shfl(dg, base + 0, 64);
    double dg_v   = __shfl(dg, base + 1, 64);
    double dg_uv  = __shfl(dg, base + 2, 64);
    double dg_a1  = __shfl(dg, base + 3, 64);
    double lg_a0g = __shfl(lg, base + 0, 64);
    double lg_u   = __shfl(lg, base + 4, 64);
    double lg_v   = __shfl(lg, base + 5, 64);
    double lg_uv  = __shfl(lg, base + 6, 64);
    double lg_a1  = __shfl(lg, base + 7, 64);

    __shared__ double sh_stick[NK], sh_cp[NK], sh_kl[NK];
    if (j == 0) {
        const double LOG2PI = 1.8378770664093454836;
        double e_log_det = (double)D * dg_a1 - s_logB;
        // ck without the cross-cluster stick prefix (added below)
        double cp = dg_u - dg_uv + 0.5 * (e_log_det - (double)D * LOG2PI
                    - s_t2nb - (double)D / c - s_nb);
        // KL(Beta(u,v)||Beta(1,1)): constant term lgamma(2)-2*lgamma(1) = 0
        double kl_beta = lg_uv - lg_u - lg_v
            + (u - 1.0) * dg_u + (v - 1.0) * dg_v + (2.0 - u - v) * dg_uv;
        double kl_gamma = (double)D * ((a1 - a0g) * dg_a1 - lg_a1 + lg_a0g) + s_klg;
        double kl_norm = 0.5 * ((double)D * (log(c / C0v) + C0v / c - 1.0) + s_kln);
        sh_stick[k] = dg_v - dg_uv;
        sh_cp[k]    = cp;
        sh_kl[k]    = kl_beta + kl_gamma + kl_norm;
    }
    if (t < NSLOT) slots[t] = 0.0;   // zero ll partials (ws is poisoned)
    __syncthreads();

    if (t < NK) {
        double pre = 0.0;
        for (int q = 0; q < t; ++q) pre += sh_stick[q];   // exclusive prefix
        constk[t] = (float)(sh_cp[t] + pre);
    }
    if (t == 0) {
        double tot = 0.0;
        for (int q = 0; q < NK; ++q) tot += sh_kl[q];
        scal[1] = tot;
        scal[0] = 0.0;
    }
}

// ---------------- kernel 2: barrier-free MFMA maha + in-wave softmax ----------------
// 16x16x32 structure (r11: numerics-verified, occupancy reached 38%) with the
// spill fixed: __launch_bounds__(512,2) = 256-reg ceiling, NO forced cap
// (r1/r6/r7/r11 all proved hard caps -> allocator starves arch side -> spill).
// Natural allocation ~110-140 total (32 AGPR acc + ~90-110 arch, half of the
// 32x32 structure's 192). LDS/block = 64KB W + 16KB staging = 80KB exactly
// -> 2 blocks/CU (160KB) IF regs <= 128 -> 16 waves/CU (2x r10); else 1 block
// = 8 waves = r10-equivalent (bounded downside).
// Staging swizzle reworked vs r11 (1M conflicts): 128B-block-preserving
// p = (c&96)|((c+4hi)&31); reads 2-way (free); stores cover full 256B
// sub-lines per instruction (keeps r10's RMW fix).
__global__ __launch_bounds__(512, 2) void maha_kernel(
    const float* __restrict__ x,
    const float* __restrict__ constk,
    const uint4* __restrict__ Wg,      // Wh then Wl, 64 KB fragment-major
    float* __restrict__ r,
    double* __restrict__ slots) {
    __shared__ __align__(16) uint4 W[4096];          // 64 KB: Wh [0,32K), Wl [32K,64K)
    __shared__ __align__(16) float SB[8][512];       // 16 KB store-transpose staging
    const int tid = threadIdx.x;
#pragma unroll
    for (int i = 0; i < 8; ++i) W[i * 512 + tid] = Wg[i * 512 + tid];
    __syncthreads();                                  // only barrier in the kernel
    const unsigned short* Wh = (const unsigned short*)W;   // Wl at ushort ofs 16384

    const int lane = tid & 63;
    const int w    = tid >> 6;        // wave 0..7
    const int hi   = lane >> 4;       // k-group / row-group 0..3
    const int n    = lane & 15;       // point row within group / col within cluster-tile
    float* sb = SB[w];

    float ck[8];
#pragma unroll
    for (int t = 0; t < 8; ++t) ck[t] = constk[t * 16 + n];

    double dsum = 0.0;

#pragma unroll 1
    for (int it = 0; it < ITERS; ++it) {
        const long n0 = (long)blockIdx.x * (128 * ITERS) + it * 128 + w * 16;

        // A-frag x data: lane(hi,n) needs dims hi*8..+8 and 32+hi*8..+8 of row n0+n.
        const float* xr = x + (n0 + n) * NDIM + hi * 8;
        f32x4 xa0 = *(const f32x4*)(xr);
        f32x4 xa1 = *(const f32x4*)(xr + 4);
        f32x4 xb0 = *(const f32x4*)(xr + 32);
        f32x4 xb1 = *(const f32x4*)(xr + 36);

        f32x4 acc[8];                 // 8 cluster-tiles x 4 rows
#pragma unroll
        for (int t = 0; t < 8; ++t) {
            acc[t][0] = 0.f; acc[t][1] = 0.f; acc[t][2] = 0.f; acc[t][3] = 0.f;
        }

        // ---- K loop: 4 ksteps (s=0: x lo-dims, 1: x hi-dims, 2: y lo, 3: y hi) ----
#pragma unroll
        for (int s = 0; s < 4; ++s) {
            float fe[8], lo[8];
#pragma unroll
            for (int e = 0; e < 8; ++e) {
                float xv = (s & 1) ? ((e < 4) ? xb0[e] : xb1[e - 4])
                                   : ((e < 4) ? xa0[e] : xa1[e - 4]);
                fe[e] = (s < 2) ? xv : fmaf(xv, xv, -1.0f);   // x or y=x^2-1
            }
#pragma unroll
            for (int e = 0; e < 8; ++e) {
                float h = __uint_as_float(__float_as_uint(fe[e]) & 0xffff0000u);
                lo[e] = fe[e] - h;
            }
            union { bf16x8 v; unsigned d[4]; } ah, al;
#pragma unroll
            for (int q = 0; q < 4; ++q) {
                ah.d[q] = pack_bf16_hi(fe[2 * q], fe[2 * q + 1]);
                al.d[q] = pack_bf16_hi(lo[2 * q], lo[2 * q + 1]);
            }
            __builtin_amdgcn_s_setprio(1);
#pragma unroll
            for (int t = 0; t < 8; ++t) {
                const int bo = ((s * 8 + t) * 4 + hi) * 128 + n * 8;
                bf16x8 bh = *(const bf16x8*)(Wh + bo);
                bf16x8 bl = *(const bf16x8*)(Wh + 16384 + bo);
                acc[t] = __builtin_amdgcn_mfma_f32_16x16x32_bf16(ah.v, bh, acc[t], 0, 0, 0);
                acc[t] = __builtin_amdgcn_mfma_f32_16x16x32_bf16(al.v, bh, acc[t], 0, 0, 0);
                acc[t] = __builtin_amdgcn_mfma_f32_16x16x32_bf16(ah.v, bl, acc[t], 0, 0, 0);
            }
            __builtin_amdgcn_s_setprio(0);
        }

        // ---- softmax + full-row store, per reg (4 rows at a time, one per group) ----
        // C/D: col = n (cluster t*16+n), row = hi*4 + reg (r11-verified layout).
        // Reduce over 128 clusters = 8 local values + 16-lane all-DPP butterfly.
#pragma unroll
        for (int reg = 0; reg < 4; ++reg) {
            float l[8];
#pragma unroll
            for (int t = 0; t < 8; ++t) l[t] = acc[t][reg] + ck[t];
            float M = fmaxf(fmaxf(fmaxf(l[0], l[1]), fmaxf(l[2], l[3])),
                            fmaxf(fmaxf(l[4], l[5]), fmaxf(l[6], l[7])));
            M = fmaxf(M, dpp_mov<0xB1>(M));    // xor1
            M = fmaxf(M, dpp_mov<0x4E>(M));    // xor2
            M = fmaxf(M, dpp_mov<0x124>(M));   // row_ror:4
            M = fmaxf(M, dpp_mov<0x128>(M));   // row_ror:8
            float e[8];
#pragma unroll
            for (int t = 0; t < 8; ++t) e[t] = __expf(l[t] - M);
            float S = ((e[0] + e[1]) + (e[2] + e[3])) + ((e[4] + e[5]) + (e[6] + e[7]));
            S += dpp_mov<0xB1>(S);
            S += dpp_mov<0x4E>(S);
            S += dpp_mov<0x124>(S);
            S += dpp_mov<0x128>(S);
            const float inv = __builtin_amdgcn_rcpf(S);

            // stage row hi: logical col c=16t+n at phys (c&96)|((c+4hi)&31)
            // (128B-block-preserving rotation; write conflicts <=4-way on few banks)
#pragma unroll
            for (int t = 0; t < 8; ++t) {
                const int c = 16 * t + n;
                sb[hi * 128 + ((c & 96) | ((c + 4 * hi) & 31))] = e[t] * inv;
            }
            // read back: phys q and q+64 (2-way bank aliasing = free);
            // logical col o = (q&96)|((q-4hi)&31); 16-lane group covers the
            // full 512B row as 2x 256B fully-covered sub-lines (no RMW).
            const int q1 = 4 * n, q2 = 64 + 4 * n;
            f32x4 v1 = *(const f32x4*)(sb + hi * 128 + q1);
            f32x4 v2 = *(const f32x4*)(sb + hi * 128 + q2);
            const int o1 = (q1 & 96) | ((q1 - 4 * hi) & 31);
            const int o2 = (q2 & 96) | ((q2 - 4 * hi) & 31);
            float* rp = r + (n0 + hi * 4 + reg) * (long)NK;
            *(f32x4*)(rp + o1) = v1;
            *(f32x4*)(rp + o2) = v2;
            dsum += (double)(M + __logf(S));   // uniform within 16-lane group
        }
    }

    // ---- ll: each group covers distinct rows; combine 4 groups, 1 atomic/wave ----
    double dtot = __shfl(dsum, 0, 64) + __shfl(dsum, 16, 64)
                + __shfl(dsum, 32, 64) + __shfl(dsum, 48, 64);
    if (lane == 0) atomicAdd(&slots[(blockIdx.x * 8 + w) & (NSLOT - 1)], dtot);
}

// ---------------- kernel 3: finalize scalar ----------------
__global__ void finalize_kernel(const double* __restrict__ scal,
                                const double* __restrict__ slots,
                                float* __restrict__ out) {
    double ll = 0.0;
    for (int i = 0; i < NSLOT; ++i) ll += slots[i];
    out[0] = (float)(scal[1] - ll);   // -elbo = kl_total - ll
}

extern "C" void kernel_launch(void* const* d_in, const int* in_sizes, int n_in,
                              void* d_out, int out_size, void* d_ws, size_t ws_size,
                              hipStream_t stream) {
    const float* x       = (const float*)d_in[0];
    const float* nat_u   = (const float*)d_in[1];
    const float* nat_v   = (const float*)d_in[2];
    const float* nat_tau = (const float*)d_in[3];
    const float* nat_c   = (const float*)d_in[4];
    const float* nat_n   = (const float*)d_in[5];
    const float* nat_B   = (const float*)d_in[6];

    const int N = in_sizes[0] / NDIM;
    float* out = (float*)d_out;

    // ws layout: scal 16B | slots 512B | constk 512B | Wh 32KB | Wl 32KB (16B-aligned)
    double* scal       = (double*)d_ws;
    double* slots      = (double*)((char*)d_ws + 16);
    float* constk      = (float*)((char*)d_ws + 16 + 512);
    unsigned short* Wh = (unsigned short*)((char*)d_ws + 1040);
    unsigned short* Wl = (unsigned short*)((char*)d_ws + 1040 + 32768);
    const uint4* Wg    = (const uint4*)((char*)d_ws + 1040);

    prep_kernel<<<1, 1024, 0, stream>>>(nat_u, nat_v, nat_tau, nat_c, nat_n, nat_B,
                                        scal, slots, constk, Wh, Wl);
    maha_kernel<<<N / (128 * ITERS), 512, 0, stream>>>(x, constk, Wg, out, slots);
    finalize_kernel<<<1, 1, 0, stream>>>(scal, slots, out + (size_t)N * NK);
}